// Round 1
// baseline (149.373 us; speedup 1.0000x reference)
//
#include <hip/hip_runtime.h>

// QuantizationLayer: 3-bit successive-approximation soft ADC.
//   Q2 = tanh(A*(x - Wn5*VR + D))
//   Q1 = tanh(A*(x - (Wn4*VR + (Q2+1)*.5*Wn3*VR) + D))
//   Q0 = tanh(A*(x - (Wn2*VR + (Q1+1)*.5*Wn1*VR + (Q2+1)*.5*Wn0*VR) + D))
//   q  = (Q0+1)*.1125 + (Q1+1)*.225 + (Q2+1)*.45
// Outputs flat: q [LA], Q [LA*3] (innermost dim = bit), Wn [6].
// Memory-bound: 503 MB total traffic -> ~80us floor at 6.3 TB/s.

__device__ __forceinline__ float fast_tanh(float z) {
    // tanh(z) = 1 - 2/(exp(2z)+1). Saturates correctly: exp->inf => 1, exp->0 => -1.
    float e = __expf(2.0f * z);
    return 1.0f - 2.0f / (e + 1.0f);
}

__global__ void __launch_bounds__(256)
quant_kernel(const float* __restrict__ x,
             const float* __restrict__ W,
             const float* __restrict__ nz,
             float* __restrict__ out,
             int la /* = L*NUM_ADCS, divisible by 4 */) {
    // Wn (6 scalars) — same-address broadcast loads, L1-resident.
    const float wn0 = W[0] + nz[0];
    const float wn1 = W[1] + nz[1];
    const float wn2 = W[2] + nz[2];
    const float wn3 = W[3] + nz[3];
    const float wn4 = W[4] + nz[4];
    const float wn5 = W[5] + nz[5];

    const float VR   = 0.225f;           // 1.8 / 2^3
    const float AMP  = 10000.0f;
    const float DLT  = 1e-30f;
    const float s2   = wn5 * VR;
    const float b1   = wn4 * VR;
    const float a1   = 0.5f * wn3 * VR;
    const float b0   = wn2 * VR;
    const float a01  = 0.5f * wn1 * VR;
    const float a02  = 0.5f * wn0 * VR;
    const float w0   = 0.5f * VR;        // 0.1125
    const float w1   = VR;               // 0.225
    const float w2   = 2.0f * VR;        // 0.45

    const long n4 = (long)la >> 2;                 // float4 groups
    const long stride = (long)gridDim.x * blockDim.x;
    float* __restrict__ qout = out;                // [la]
    float* __restrict__ Qout = out + (long)la;     // [la*3]

    for (long i = (long)blockIdx.x * blockDim.x + threadIdx.x; i < n4; i += stride) {
        const float4 xv = reinterpret_cast<const float4*>(x)[i];
        const float xs[4] = {xv.x, xv.y, xv.z, xv.w};
        float q[4];
        float Qv[12];
        #pragma unroll
        for (int k = 0; k < 4; ++k) {
            const float xe = xs[k];
            const float Q2 = fast_tanh(AMP * (xe - s2 + DLT));
            const float Q1 = fast_tanh(AMP * (xe - (b1 + (Q2 + 1.0f) * a1) + DLT));
            const float Q0 = fast_tanh(AMP * (xe - (b0 + (Q1 + 1.0f) * a01
                                                       + (Q2 + 1.0f) * a02) + DLT));
            q[k] = (Q0 + 1.0f) * w0 + (Q1 + 1.0f) * w1 + (Q2 + 1.0f) * w2;
            Qv[k * 3 + 0] = Q0;
            Qv[k * 3 + 1] = Q1;
            Qv[k * 3 + 2] = Q2;
        }
        reinterpret_cast<float4*>(qout)[i] = make_float4(q[0], q[1], q[2], q[3]);
        // 12 contiguous floats at byte offset i*48 — 16B-aligned, 3x float4.
        float4* qp = reinterpret_cast<float4*>(Qout + i * 12);
        qp[0] = make_float4(Qv[0], Qv[1], Qv[2],  Qv[3]);
        qp[1] = make_float4(Qv[4], Qv[5], Qv[6],  Qv[7]);
        qp[2] = make_float4(Qv[8], Qv[9], Qv[10], Qv[11]);
    }

    // Wn passthrough output: 6 floats at tail.
    if (blockIdx.x == 0 && threadIdx.x < 6) {
        out[(long)la * 4 + threadIdx.x] = W[threadIdx.x] + nz[threadIdx.x];
    }
}

extern "C" void kernel_launch(void* const* d_in, const int* in_sizes, int n_in,
                              void* d_out, int out_size, void* d_ws, size_t ws_size,
                              hipStream_t stream) {
    const float* x  = (const float*)d_in[0];
    const float* W  = (const float*)d_in[1];
    const float* nz = (const float*)d_in[2];
    float* out = (float*)d_out;
    const int la = in_sizes[0];            // 25165824

    const int block = 256;
    const int grid = 2048;                 // 256 CU x 8 blocks, grid-stride
    quant_kernel<<<grid, block, 0, stream>>>(x, W, nz, out, la);
}

// Round 2
// 90.477 us; speedup vs baseline: 1.6509x; 1.6509x over previous
//
#include <hip/hip_runtime.h>

// QuantizationLayer: 3-bit successive-approximation soft ADC (see R0 notes).
// Outputs flat: q [la], Q [la*3] (innermost dim = bit), Wn [6].
// R1: 149us @ 3.37 TB/s -- Q stores (stride-48B/lane) uncoalesced.
// R2: stage Q through LDS so all global stores are lane-contiguous float4.
//     Block = 256 threads x 4 elems = 1024 contiguous elements; Q chunk =
//     12KB contiguous, written as 3 coalesced float4 stores per thread.
//     LDS write at t*48B is bank-conflict-free (12t mod 32 covers all banks).

__device__ __forceinline__ float fast_tanh(float z) {
    // tanh(z) = 1 - 2/(exp(2z)+1); saturates correctly at +/-inf.
    float e = __expf(2.0f * z);
    return 1.0f - 2.0f / (e + 1.0f);
}

__global__ void __launch_bounds__(256)
quant_kernel(const float* __restrict__ x,
             const float* __restrict__ W,
             const float* __restrict__ nz,
             float* __restrict__ out,
             int la /* = L*NUM_ADCS */) {
    __shared__ float lds[3072];  // 12 KB Q staging

    // Wn scalars — same-address broadcast loads.
    const float wn0 = W[0] + nz[0];
    const float wn1 = W[1] + nz[1];
    const float wn2 = W[2] + nz[2];
    const float wn3 = W[3] + nz[3];
    const float wn4 = W[4] + nz[4];
    const float wn5 = W[5] + nz[5];

    const float VR  = 0.225f;
    const float AMP = 10000.0f;
    const float DLT = 1e-30f;
    const float s2  = wn5 * VR;
    const float b1  = wn4 * VR;
    const float a1  = 0.5f * wn3 * VR;
    const float b0  = wn2 * VR;
    const float a01 = 0.5f * wn1 * VR;
    const float a02 = 0.5f * wn0 * VR;
    const float w0  = 0.5f * VR;
    const float w1  = VR;
    const float w2  = 2.0f * VR;

    const int  t     = threadIdx.x;
    const long base  = (long)blockIdx.x * 1024;   // element base of this block
    float* __restrict__ Qout = out + (long)la;    // [la*3]

    if (base + 1024 <= (long)la) {
        // ---- fast path: full 1024-element chunk ----
        const float4 xv = reinterpret_cast<const float4*>(x + base)[t];
        const float xs[4] = {xv.x, xv.y, xv.z, xv.w};
        float q[4], Qv[12];
        #pragma unroll
        for (int k = 0; k < 4; ++k) {
            const float xe = xs[k];
            const float Q2 = fast_tanh(AMP * (xe - s2 + DLT));
            const float Q1 = fast_tanh(AMP * (xe - (b1 + (Q2 + 1.0f) * a1) + DLT));
            const float Q0 = fast_tanh(AMP * (xe - (b0 + (Q1 + 1.0f) * a01
                                                       + (Q2 + 1.0f) * a02) + DLT));
            q[k] = (Q0 + 1.0f) * w0 + (Q1 + 1.0f) * w1 + (Q2 + 1.0f) * w2;
            Qv[k * 3 + 0] = Q0;
            Qv[k * 3 + 1] = Q1;
            Qv[k * 3 + 2] = Q2;
        }
        reinterpret_cast<float4*>(out + base)[t] =
            make_float4(q[0], q[1], q[2], q[3]);

        // Stage Q in LDS (stride-48B writes: conflict-free).
        float4* lp = reinterpret_cast<float4*>(&lds[t * 12]);
        lp[0] = make_float4(Qv[0], Qv[1], Qv[2],  Qv[3]);
        lp[1] = make_float4(Qv[4], Qv[5], Qv[6],  Qv[7]);
        lp[2] = make_float4(Qv[8], Qv[9], Qv[10], Qv[11]);
        __syncthreads();

        // Coalesced Q writes: 768 contiguous float4s per block.
        float4* __restrict__ Qg = reinterpret_cast<float4*>(Qout + base * 3);
        const float4* ls = reinterpret_cast<const float4*>(lds);
        Qg[t]       = ls[t];
        Qg[t + 256] = ls[t + 256];
        Qg[t + 512] = ls[t + 512];
    } else {
        // ---- tail path: per-element guarded (not hit at la=25165824) ----
        for (int k = 0; k < 4; ++k) {
            const long e = base + t * 4 + k;
            if (e >= (long)la) break;
            const float xe = x[e];
            const float Q2 = fast_tanh(AMP * (xe - s2 + DLT));
            const float Q1 = fast_tanh(AMP * (xe - (b1 + (Q2 + 1.0f) * a1) + DLT));
            const float Q0 = fast_tanh(AMP * (xe - (b0 + (Q1 + 1.0f) * a01
                                                       + (Q2 + 1.0f) * a02) + DLT));
            out[e] = (Q0 + 1.0f) * w0 + (Q1 + 1.0f) * w1 + (Q2 + 1.0f) * w2;
            Qout[e * 3 + 0] = Q0;
            Qout[e * 3 + 1] = Q1;
            Qout[e * 3 + 2] = Q2;
        }
    }

    // Wn passthrough output: 6 floats at tail of out.
    if (blockIdx.x == 0 && t < 6) {
        out[(long)la * 4 + t] = W[t] + nz[t];
    }
}

extern "C" void kernel_launch(void* const* d_in, const int* in_sizes, int n_in,
                              void* d_out, int out_size, void* d_ws, size_t ws_size,
                              hipStream_t stream) {
    const float* x  = (const float*)d_in[0];
    const float* W  = (const float*)d_in[1];
    const float* nz = (const float*)d_in[2];
    float* out = (float*)d_out;
    const int la = in_sizes[0];            // 25165824

    const int block = 256;
    const int grid = (la + 1023) / 1024;   // 24576 blocks: 1024 elems each
    quant_kernel<<<grid, block, 0, stream>>>(x, W, nz, out, la);
}